// Round 7
// baseline (48.686 us; speedup 1.0000x reference)
//
#include <hip/hip_runtime.h>

constexpr int   BATCH        = 16384;
constexpr int   CELLS        = 802816;            // BATCH * 49
constexpr int   F            = 30;
constexpr int   CPT          = 64;                // cells per tile = 1 wave's tile
constexpr int   NTILES       = CELLS / CPT;       // 12544 exact
constexpr int   TILE_B       = CPT * F * 4;       // 7680 B per input per tile
constexpr int   GRID         = 1280;              // 5 blocks (waves) per CU
constexpr float LAMBDA_COORD = 5.0f;
constexpr float LAMBDA_NOOBJ = 0.5f;
constexpr float EPS_WH       = 1e-6f;
constexpr float EPS_IOU      = 1e-6f;

__device__ __forceinline__ void load_lds16(const void* g, void* l) {
    __builtin_amdgcn_global_load_lds(
        (const __attribute__((address_space(1))) unsigned int*)g,
        (__attribute__((address_space(3))) unsigned int*)l,
        16, 0, 0);
}
__device__ __forceinline__ void load_lds4(const void* g, void* l) {
    __builtin_amdgcn_global_load_lds(
        (const __attribute__((address_space(1))) unsigned int*)g,
        (__attribute__((address_space(3))) unsigned int*)l,
        4, 0, 0);
}

// Stage one 64-cell tile (both inputs) with 18 DMA instructions:
// per input 7680 B = 7 x 1024 B (16 B/lane) + 2 x 256 B (4 B/lane).
__device__ __forceinline__ void stage_tile(const char* tg, const char* pg,
                                           char* lt, char* lp, int lane) {
#pragma unroll
    for (int j = 0; j < 7; ++j) {
        load_lds16(tg + j * 1024 + lane * 16, lt + j * 1024);
        load_lds16(pg + j * 1024 + lane * 16, lp + j * 1024);
    }
#pragma unroll
    for (int j = 0; j < 2; ++j) {
        load_lds4(tg + 7168 + j * 256 + lane * 4, lt + 7168 + j * 256);
        load_lds4(pg + 7168 + j * 256 + lane * 4, lp + 7168 + j * 256);
    }
}

__device__ __forceinline__ float iou_yolo(const float b0, const float b1,
                                          const float b2, const float b3,
                                          const float c0, const float c1,
                                          const float c2, const float c3) {
    float b1x1 = b0 - b2 * 0.5f;
    float b1y1 = b1 - b3 * 0.5f;
    float b1x2 = b0 + b2 * 0.5f;
    float b1y2 = b1 + b3 * 0.5f;
    float b2x1 = c0 - c2 * 0.5f;
    float b2y1 = c1 - c3 * 0.5f;
    float b2x2 = c0 + c2 * 0.5f;
    float b2y2 = c1 + c3 * 0.5f;
    float iw = fmaxf(fminf(b1x2, b2x2) - fmaxf(b1x1, b2x1), 0.0f);
    float ih = fmaxf(fminf(b1y2, b2y2) - fmaxf(b1y1, b2y1), 0.0f);
    float inter = iw * ih;
    float a1 = fabsf((b1x2 - b1x1) * (b1y2 - b1y1));
    float a2 = fabsf((b2x2 - b2x1) * (b2y2 - b2y1));
    return inter / (a1 + a2 - inter + EPS_IOU);
}

__global__ void __launch_bounds__(64)
yolo_loss_kernel(const float* __restrict__ yt_g,
                 const float* __restrict__ yp_g,
                 float* __restrict__ out) {
    // One wave per block. [buffer][input(t/p)][tile floats] = 30720 B.
    __shared__ __align__(16) float lbuf[2][2][CPT * F];

    const int lane = threadIdx.x;    // 0..63

    // ---- Prologue: stage first tile into buffer 0 ----
    int tile = blockIdx.x;
    stage_tile((const char*)yt_g + (size_t)tile * TILE_B,
               (const char*)yp_g + (size_t)tile * TILE_B,
               (char*)lbuf[0][0], (char*)lbuf[0][1], lane);

    float acc = 0.0f;
    int buf = 0;

    for (; tile < NTILES; tile += GRID) {
        const int next = tile + GRID;
        if (next < NTILES) {         // wave-uniform branch
            // Prefetch next tile into the other buffer; don't wait for it.
            stage_tile((const char*)yt_g + (size_t)next * TILE_B,
                       (const char*)yp_g + (size_t)next * TILE_B,
                       (char*)lbuf[buf ^ 1][0], (char*)lbuf[buf ^ 1][1], lane);
            // Wait only for the CURRENT tile's 18 loads (18 newer stay in flight).
            asm volatile("s_waitcnt vmcnt(18)" ::: "memory");
        } else {
            asm volatile("s_waitcnt vmcnt(0)" ::: "memory");
        }
        // Single wave: program order + vmcnt is enough — NO barrier.

        const float2* t2 = reinterpret_cast<const float2*>(&lbuf[buf][0][lane * F]);
        const float2* p2 = reinterpret_cast<const float2*>(&lbuf[buf][1][lane * F]);
        float t[F], p[F];
        {   // t: channels 0..4 and 10..29 (5..9 dead)
            float2 v;
            v = t2[0]; t[0] = v.x; t[1] = v.y;
            v = t2[1]; t[2] = v.x; t[3] = v.y;
            v = t2[2]; t[4] = v.x;
#pragma unroll
            for (int k = 5; k < 15; ++k) { v = t2[k]; t[2 * k] = v.x; t[2 * k + 1] = v.y; }
        }
#pragma unroll
        for (int k = 0; k < 15; ++k) { float2 w = p2[k]; p[2 * k] = w.x; p[2 * k + 1] = w.y; }

        const float objf   = (t[4] == 1.0f) ? 1.0f : 0.0f;
        const float noobjf = 1.0f - objf;

        const float iou1 = iou_yolo(t[0], t[1], t[2], t[3], p[0], p[1], p[2], p[3]);
        const float iou2 = iou_yolo(t[0], t[1], t[2], t[3], p[5], p[6], p[7], p[8]);
        const bool  best1 = iou1 > iou2;

        const float bh0 = best1 ? p[0] : p[5];
        const float bh1 = best1 ? p[1] : p[6];
        const float bh2 = best1 ? p[2] : p[7];
        const float bh3 = best1 ? p[3] : p[8];
        const float confhat = best1 ? p[4] : p[9];

        const float dx = t[0] - bh0;
        const float dy = t[1] - bh1;
        const float xy = dx * dx + dy * dy;

        const float wt = sqrtf(t[2]) - sqrtf(fabsf(bh2 + EPS_WH));
        const float ht = sqrtf(t[3]) - sqrtf(fabsf(bh3 + EPS_WH));
        const float wh = wt * wt + ht * ht;

        const float dc = t[4] - confhat;

        float cls = 0.0f;
#pragma unroll
        for (int c = 10; c < F; ++c) {
            const float d = t[c] - p[c];
            cls += d * d;
        }
        // noobj: reference slices yp[..., 4::5] -> channels 4,9,14,19,24,29
        float noobj = 0.0f;
#pragma unroll
        for (int c = 4; c < F; c += 5) {
            const float d = t[4] - p[c];
            noobj += d * d;
        }

        acc += objf * (LAMBDA_COORD * (xy + wh) + dc * dc + cls)
             + noobjf * (LAMBDA_NOOBJ * noobj);

        buf ^= 1;
    }

    // ---- Wave shuffle reduction -> one atomic per block ----
#pragma unroll
    for (int off = 32; off > 0; off >>= 1) acc += __shfl_down(acc, off);
    if (lane == 0) atomicAdd(out, acc * (1.0f / (float)BATCH));
}

extern "C" void kernel_launch(void* const* d_in, const int* in_sizes, int n_in,
                              void* d_out, int out_size, void* d_ws, size_t ws_size,
                              hipStream_t stream) {
    const float* y_trues = (const float*)d_in[0];
    const float* y_preds = (const float*)d_in[1];
    float* out = (float*)d_out;

    // Harness poisons d_out once, never re-poisons between replays: zero it every call.
    hipMemsetAsync(out, 0, sizeof(float) * (size_t)out_size, stream);

    yolo_loss_kernel<<<GRID, 64, 0, stream>>>(y_trues, y_preds, out);
}

// Round 8
// 41.406 us; speedup vs baseline: 1.1758x; 1.1758x over previous
//
#include <hip/hip_runtime.h>

constexpr int   BATCH        = 16384;
constexpr int   CELLS        = 802816;            // BATCH * 49
constexpr int   F            = 30;
constexpr int   CPT          = 64;                // cells per wave-tile
constexpr int   NTILES       = CELLS / CPT;       // 12544 exact
constexpr int   TILE_B       = CPT * F * 4;       // 7680 B per input per tile
constexpr int   GRID         = 512;               // 2 blocks/CU, 2 waves/block
constexpr int   NWAVES       = GRID * 2;          // 1024 wave-pipelines
constexpr float LAMBDA_COORD = 5.0f;
constexpr float LAMBDA_NOOBJ = 0.5f;
constexpr float EPS_WH       = 1e-6f;
constexpr float EPS_IOU      = 1e-6f;

__device__ __forceinline__ void load_lds16(const void* g, void* l) {
    __builtin_amdgcn_global_load_lds(
        (const __attribute__((address_space(1))) unsigned int*)g,
        (__attribute__((address_space(3))) unsigned int*)l,
        16, 0, 0);
}
__device__ __forceinline__ void load_lds4(const void* g, void* l) {
    __builtin_amdgcn_global_load_lds(
        (const __attribute__((address_space(1))) unsigned int*)g,
        (__attribute__((address_space(3))) unsigned int*)l,
        4, 0, 0);
}

// Stage one 64-cell tile (both inputs) with 18 DMA instructions:
// per input 7680 B = 7 x 1024 B (16 B/lane) + 2 x 256 B (4 B/lane).
__device__ __forceinline__ void stage_tile(const char* tg, const char* pg,
                                           char* lt, char* lp, int lane) {
#pragma unroll
    for (int j = 0; j < 7; ++j) {
        load_lds16(tg + j * 1024 + lane * 16, lt + j * 1024);
        load_lds16(pg + j * 1024 + lane * 16, lp + j * 1024);
    }
#pragma unroll
    for (int j = 0; j < 2; ++j) {
        load_lds4(tg + 7168 + j * 256 + lane * 4, lt + 7168 + j * 256);
        load_lds4(pg + 7168 + j * 256 + lane * 4, lp + 7168 + j * 256);
    }
}

__device__ __forceinline__ float iou_yolo(const float b0, const float b1,
                                          const float b2, const float b3,
                                          const float c0, const float c1,
                                          const float c2, const float c3) {
    float b1x1 = b0 - b2 * 0.5f;
    float b1y1 = b1 - b3 * 0.5f;
    float b1x2 = b0 + b2 * 0.5f;
    float b1y2 = b1 + b3 * 0.5f;
    float b2x1 = c0 - c2 * 0.5f;
    float b2y1 = c1 - c3 * 0.5f;
    float b2x2 = c0 + c2 * 0.5f;
    float b2y2 = c1 + c3 * 0.5f;
    float iw = fmaxf(fminf(b1x2, b2x2) - fmaxf(b1x1, b2x1), 0.0f);
    float ih = fmaxf(fminf(b1y2, b2y2) - fmaxf(b1y1, b2y1), 0.0f);
    float inter = iw * ih;
    float a1 = fabsf((b1x2 - b1x1) * (b1y2 - b1y1));
    float a2 = fabsf((b2x2 - b2x1) * (b2y2 - b2y1));
    return inter / (a1 + a2 - inter + EPS_IOU);
}

__global__ void __launch_bounds__(128)
yolo_loss_kernel(const float* __restrict__ yt_g,
                 const float* __restrict__ yp_g,
                 float* __restrict__ out) {
    // Wave-private double-buffered tile pairs: [wave][buf][input][1920 floats] = 61440 B.
    __shared__ __align__(16) float lbuf[2][2][2][CPT * F];

    const int tid  = threadIdx.x;
    const int lane = tid & 63;
    const int wid  = tid >> 6;
    const int wgid = blockIdx.x * 2 + wid;    // global wave id, 0..1023

    // ---- Prologue: stage this wave's first tile into its buffer 0 ----
    int tile = wgid;
    stage_tile((const char*)yt_g + (size_t)tile * TILE_B,
               (const char*)yp_g + (size_t)tile * TILE_B,
               (char*)lbuf[wid][0][0], (char*)lbuf[wid][0][1], lane);

    float acc = 0.0f;
    int buf = 0;

    for (; tile < NTILES; tile += NWAVES) {
        const int next = tile + NWAVES;
        if (next < NTILES) {                  // wave-uniform branch
            // Prefetch next tile into the other buffer; don't wait for it.
            stage_tile((const char*)yt_g + (size_t)next * TILE_B,
                       (const char*)yp_g + (size_t)next * TILE_B,
                       (char*)lbuf[wid][buf ^ 1][0], (char*)lbuf[wid][buf ^ 1][1], lane);
            // Wait only for the CURRENT tile's 18 loads (18 newer stay in flight).
            asm volatile("s_waitcnt vmcnt(18)" ::: "memory");
        } else {
            asm volatile("s_waitcnt vmcnt(0)" ::: "memory");
        }
        // Wave-private LDS + per-wave vmcnt ordering: NO barrier needed.

        const float2* t2 = reinterpret_cast<const float2*>(&lbuf[wid][buf][0][lane * F]);
        const float2* p2 = reinterpret_cast<const float2*>(&lbuf[wid][buf][1][lane * F]);
        float t[F], p[F];
        {   // t: channels 0..4 and 10..29 (5..9 dead)
            float2 v;
            v = t2[0]; t[0] = v.x; t[1] = v.y;
            v = t2[1]; t[2] = v.x; t[3] = v.y;
            v = t2[2]; t[4] = v.x;
#pragma unroll
            for (int k = 5; k < 15; ++k) { v = t2[k]; t[2 * k] = v.x; t[2 * k + 1] = v.y; }
        }
#pragma unroll
        for (int k = 0; k < 15; ++k) { float2 w = p2[k]; p[2 * k] = w.x; p[2 * k + 1] = w.y; }

        const float objf   = (t[4] == 1.0f) ? 1.0f : 0.0f;
        const float noobjf = 1.0f - objf;

        const float iou1 = iou_yolo(t[0], t[1], t[2], t[3], p[0], p[1], p[2], p[3]);
        const float iou2 = iou_yolo(t[0], t[1], t[2], t[3], p[5], p[6], p[7], p[8]);
        const bool  best1 = iou1 > iou2;

        const float bh0 = best1 ? p[0] : p[5];
        const float bh1 = best1 ? p[1] : p[6];
        const float bh2 = best1 ? p[2] : p[7];
        const float bh3 = best1 ? p[3] : p[8];
        const float confhat = best1 ? p[4] : p[9];

        const float dx = t[0] - bh0;
        const float dy = t[1] - bh1;
        const float xy = dx * dx + dy * dy;

        const float wt = sqrtf(t[2]) - sqrtf(fabsf(bh2 + EPS_WH));
        const float ht = sqrtf(t[3]) - sqrtf(fabsf(bh3 + EPS_WH));
        const float wh = wt * wt + ht * ht;

        const float dc = t[4] - confhat;

        float cls = 0.0f;
#pragma unroll
        for (int c = 10; c < F; ++c) {
            const float d = t[c] - p[c];
            cls += d * d;
        }
        // noobj: reference slices yp[..., 4::5] -> channels 4,9,14,19,24,29
        float noobj = 0.0f;
#pragma unroll
        for (int c = 4; c < F; c += 5) {
            const float d = t[4] - p[c];
            noobj += d * d;
        }

        acc += objf * (LAMBDA_COORD * (xy + wh) + dc * dc + cls)
             + noobjf * (LAMBDA_NOOBJ * noobj);

        buf ^= 1;
    }

    // ---- Wave shuffle reduction -> block LDS -> one atomic per block ----
#pragma unroll
    for (int off = 32; off > 0; off >>= 1) acc += __shfl_down(acc, off);

    __shared__ float wsum[2];
    if (lane == 0) wsum[wid] = acc;
    __syncthreads();
    if (tid == 0) atomicAdd(out, (wsum[0] + wsum[1]) * (1.0f / (float)BATCH));
}

extern "C" void kernel_launch(void* const* d_in, const int* in_sizes, int n_in,
                              void* d_out, int out_size, void* d_ws, size_t ws_size,
                              hipStream_t stream) {
    const float* y_trues = (const float*)d_in[0];
    const float* y_preds = (const float*)d_in[1];
    float* out = (float*)d_out;

    // Harness poisons d_out once, never re-poisons between replays: zero it every call.
    hipMemsetAsync(out, 0, sizeof(float) * (size_t)out_size, stream);

    yolo_loss_kernel<<<GRID, 128, 0, stream>>>(y_trues, y_preds, out);
}

// Round 9
// 37.956 us; speedup vs baseline: 1.2827x; 1.0909x over previous
//
#include <hip/hip_runtime.h>

constexpr int   BATCH        = 16384;
constexpr int   CELLS        = 802816;            // BATCH * 49
constexpr int   F            = 30;
constexpr int   CPT          = 64;                // cells per wave-tile
constexpr int   NTILES       = CELLS / CPT;       // 12544 exact
constexpr int   TFL2         = CPT * F / 2;       // 960 float2 per input per tile
constexpr int   GRID         = 512;               // 2 blocks/CU
constexpr int   WPB          = 4;                 // waves per block (256 threads)
constexpr int   NWAVES       = GRID * WPB;        // 2048 wave-pipelines
constexpr float LAMBDA_COORD = 5.0f;
constexpr float LAMBDA_NOOBJ = 0.5f;
constexpr float EPS_WH       = 1e-6f;
constexpr float EPS_IOU      = 1e-6f;

__device__ __forceinline__ float iou_yolo(const float b0, const float b1,
                                          const float b2, const float b3,
                                          const float c0, const float c1,
                                          const float c2, const float c3) {
    float b1x1 = b0 - b2 * 0.5f;
    float b1y1 = b1 - b3 * 0.5f;
    float b1x2 = b0 + b2 * 0.5f;
    float b1y2 = b1 + b3 * 0.5f;
    float b2x1 = c0 - c2 * 0.5f;
    float b2y1 = c1 - c3 * 0.5f;
    float b2x2 = c0 + c2 * 0.5f;
    float b2y2 = c1 + c3 * 0.5f;
    float iw = fmaxf(fminf(b1x2, b2x2) - fmaxf(b1x1, b2x1), 0.0f);
    float ih = fmaxf(fminf(b1y2, b2y2) - fmaxf(b1y1, b2y1), 0.0f);
    float inter = iw * ih;
    float a1 = fabsf((b1x2 - b1x1) * (b1y2 - b1y1));
    float a2 = fabsf((b2x2 - b2x1) * (b2y2 - b2y1));
    return inter / (a1 + a2 - inter + EPS_IOU);
}

__global__ void __launch_bounds__(256, 2)
yolo_loss_kernel(const float* __restrict__ yt_g,
                 const float* __restrict__ yp_g,
                 float* __restrict__ out) {
    // Wave-private SINGLE-buffered tile pairs: [wave][input][1920 floats] = 61440 B.
    __shared__ __align__(16) float lbuf[WPB][2][CPT * F];

    const int tid  = threadIdx.x;
    const int lane = tid & 63;
    const int wid  = tid >> 6;
    const int wgid = blockIdx.x * WPB + wid;   // global wave id, 0..2047

    const float2* tg2 = reinterpret_cast<const float2*>(yt_g);
    const float2* pg2 = reinterpret_cast<const float2*>(yp_g);
    float2* lt2 = reinterpret_cast<float2*>(lbuf[wid][0]);
    float2* lp2 = reinterpret_cast<float2*>(lbuf[wid][1]);

    float2 rt[15], rp[15];

    // ---- Prologue: load tile0 to VGPRs (coalesced), write to this wave's LDS ----
    int tile = wgid;
    {
        const size_t b2i = (size_t)tile * TFL2;
#pragma unroll
        for (int j = 0; j < 15; ++j) {
            rt[j] = tg2[b2i + lane + 64 * j];
            rp[j] = pg2[b2i + lane + 64 * j];
        }
#pragma unroll
        for (int j = 0; j < 15; ++j) {
            lt2[lane + 64 * j] = rt[j];
            lp2[lane + 64 * j] = rp[j];
        }
    }

    float acc = 0.0f;

    for (; tile < NTILES; tile += NWAVES) {
        const int next = tile + NWAVES;
        if (next < NTILES) {                   // wave-uniform branch
            // Issue next tile's coalesced loads into VGPRs — no wait yet.
            const size_t b2i = (size_t)next * TFL2;
#pragma unroll
            for (int j = 0; j < 15; ++j) {
                rt[j] = tg2[b2i + lane + 64 * j];
                rp[j] = pg2[b2i + lane + 64 * j];
            }
        }

        // ---- Compute current tile from LDS (wave-private, no barrier) ----
        const float2* t2 = reinterpret_cast<const float2*>(&lbuf[wid][0][lane * F]);
        const float2* p2 = reinterpret_cast<const float2*>(&lbuf[wid][1][lane * F]);
        float t[F], p[F];
        {   // t: channels 0..4 and 10..29 (5..9 dead)
            float2 v;
            v = t2[0]; t[0] = v.x; t[1] = v.y;
            v = t2[1]; t[2] = v.x; t[3] = v.y;
            v = t2[2]; t[4] = v.x;
#pragma unroll
            for (int k = 5; k < 15; ++k) { v = t2[k]; t[2 * k] = v.x; t[2 * k + 1] = v.y; }
        }
#pragma unroll
        for (int k = 0; k < 15; ++k) { float2 w = p2[k]; p[2 * k] = w.x; p[2 * k + 1] = w.y; }

        const float objf   = (t[4] == 1.0f) ? 1.0f : 0.0f;
        const float noobjf = 1.0f - objf;

        const float iou1 = iou_yolo(t[0], t[1], t[2], t[3], p[0], p[1], p[2], p[3]);
        const float iou2 = iou_yolo(t[0], t[1], t[2], t[3], p[5], p[6], p[7], p[8]);
        const bool  best1 = iou1 > iou2;

        const float bh0 = best1 ? p[0] : p[5];
        const float bh1 = best1 ? p[1] : p[6];
        const float bh2 = best1 ? p[2] : p[7];
        const float bh3 = best1 ? p[3] : p[8];
        const float confhat = best1 ? p[4] : p[9];

        const float dx = t[0] - bh0;
        const float dy = t[1] - bh1;
        const float xy = dx * dx + dy * dy;

        const float wt = sqrtf(t[2]) - sqrtf(fabsf(bh2 + EPS_WH));
        const float ht = sqrtf(t[3]) - sqrtf(fabsf(bh3 + EPS_WH));
        const float wh = wt * wt + ht * ht;

        const float dc = t[4] - confhat;

        float cls = 0.0f;
#pragma unroll
        for (int c = 10; c < F; ++c) {
            const float d = t[c] - p[c];
            cls += d * d;
        }
        // noobj: reference slices yp[..., 4::5] -> channels 4,9,14,19,24,29
        float noobj = 0.0f;
#pragma unroll
        for (int c = 4; c < F; c += 5) {
            const float d = t[4] - p[c];
            noobj += d * d;
        }

        acc += objf * (LAMBDA_COORD * (xy + wh) + dc * dc + cls)
             + noobjf * (LAMBDA_NOOBJ * noobj);

        if (next < NTILES) {
            // All current-tile ds_reads retired (their data fed acc); fence then
            // overwrite the single buffer with the prefetched next tile.
            asm volatile("s_waitcnt lgkmcnt(0)" ::: "memory");
            asm volatile("s_waitcnt vmcnt(0)" ::: "memory");
#pragma unroll
            for (int j = 0; j < 15; ++j) {
                lt2[lane + 64 * j] = rt[j];
                lp2[lane + 64 * j] = rp[j];
            }
        }
    }

    // ---- Wave shuffle reduction -> block LDS -> one atomic per block ----
#pragma unroll
    for (int off = 32; off > 0; off >>= 1) acc += __shfl_down(acc, off);

    __shared__ float wsum[WPB];
    if (lane == 0) wsum[wid] = acc;
    __syncthreads();
    if (tid == 0) {
        float s = 0.0f;
#pragma unroll
        for (int w = 0; w < WPB; ++w) s += wsum[w];
        atomicAdd(out, s * (1.0f / (float)BATCH));
    }
}

extern "C" void kernel_launch(void* const* d_in, const int* in_sizes, int n_in,
                              void* d_out, int out_size, void* d_ws, size_t ws_size,
                              hipStream_t stream) {
    const float* y_trues = (const float*)d_in[0];
    const float* y_preds = (const float*)d_in[1];
    float* out = (float*)d_out;

    // Harness poisons d_out once, never re-poisons between replays: zero it every call.
    hipMemsetAsync(out, 0, sizeof(float) * (size_t)out_size, stream);

    yolo_loss_kernel<<<GRID, 256, 0, stream>>>(y_trues, y_preds, out);
}